// Round 3
// baseline (920.145 us; speedup 1.0000x reference)
//
#include <hip/hip_runtime.h>
#include <hip/hip_bf16.h>

static const int kN  = 25600;   // nodes
static const int kE  = 409600;  // edges
static const int kG  = 128;     // graphs
static const int kIN = 200;     // raw feature dim
static const int kIN2 = 400;    // after nan-mask concat
#define BN_EPS_ 1e-5f

__device__ __forceinline__ float wredSum(float v) {
#pragma unroll
  for (int off = 1; off < 64; off <<= 1) v += __shfl_xor(v, off, 64);
  return v;
}
__device__ __forceinline__ float wredMax(float v) {
#pragma unroll
  for (int off = 1; off < 64; off <<= 1) v = fmaxf(v, __shfl_xor(v, off, 64));
  return v;
}

// zero n 32-bit words
__global__ void k_zero(unsigned int* __restrict__ p, int n) {
  int i = blockIdx.x * blockDim.x + threadIdx.x;
  if (i < n) p[i] = 0u;
}

// ---------------- preprocessing ----------------

// x[N,200] f32 -> x2[N,400] f32 = [nan_to_num(x), isnan(x)]
__global__ void k_prep_x(const float* __restrict__ x, float* __restrict__ x2) {
  int i = blockIdx.x * blockDim.x + threadIdx.x;
  if (i >= kN * kIN) return;
  int n = i / kIN, j = i - n * kIN;
  float v = x[i];
  bool bad = (v != v);
  x2[(size_t)n * kIN2 + j] = bad ? 0.f : v;
  x2[(size_t)n * kIN2 + kIN + j] = bad ? 1.f : 0.f;
}

// per-dst in-degree + sum of nan_to_num(edge_attr)
__global__ void k_edge_deg(const int* __restrict__ ei, const float* __restrict__ ea,
                           int* __restrict__ deg, float* __restrict__ easum) {
  int e = blockIdx.x * blockDim.x + threadIdx.x;
  if (e >= kE) return;
  int d = ei[kE + e];
  atomicAdd(&deg[d], 1);
  float v = ea[e];
  if (v != v) v = 0.f;
  atomicAdd(&easum[d], v);
}

// exclusive scan of deg -> rowp  (25 chunks of 1024; kN == 25*1024)
__global__ void k_scan_chunk(const int* __restrict__ deg, int* __restrict__ rowp,
                             int* __restrict__ csum) {
  __shared__ int s[1024];
  int tid = threadIdx.x;
  int i = blockIdx.x * 1024 + tid;
  int v = deg[i];
  s[tid] = v;
  __syncthreads();
  for (int off = 1; off < 1024; off <<= 1) {
    int t = (tid >= off) ? s[tid - off] : 0;
    __syncthreads();
    s[tid] += t;
    __syncthreads();
  }
  rowp[i] = s[tid] - v;  // exclusive within chunk
  if (tid == 1023) csum[blockIdx.x] = s[tid];
}

__global__ void k_scan_sums(const int* __restrict__ csum, int* __restrict__ coff, int nchunk) {
  if (threadIdx.x == 0 && blockIdx.x == 0) {
    int acc = 0;
    for (int i = 0; i < nchunk; i++) { coff[i] = acc; acc += csum[i]; }
  }
}

__global__ void k_scan_fix(int* __restrict__ rowp, const int* __restrict__ coff,
                           const int* __restrict__ deg, const float* __restrict__ easum,
                           float* __restrict__ lea) {
  int i = blockIdx.x * blockDim.x + threadIdx.x;
  if (i >= kN) return;
  rowp[i] += coff[i >> 10];
  float c = (float)deg[i];
  lea[i] = easum[i] / fmaxf(c, 1.f);  // mean incoming edge attr (self-loop fill)
}

__global__ void k_scatter(const int* __restrict__ ei, const int* __restrict__ rowp,
                          int* __restrict__ cur, int* __restrict__ eidl) {
  int e = blockIdx.x * blockDim.x + threadIdx.x;
  if (e >= kE) return;
  int d = ei[kE + e];
  int pos = atomicAdd(&cur[d], 1);
  eidl[rowp[d] + pos] = e;
}

// ---------------- GEMM: C[M,N] = A[M,K] @ B[K,N], fp32 ----------------
// 64x64 tile, 256 threads, 4x4 micro-tile. M%64==0, N%64==0, K%8==0 hold here.
__global__ void k_gemm(const float* __restrict__ A, const float* __restrict__ B,
                       float* __restrict__ C, int M, int N, int K) {
  __shared__ float As[8][64];
  __shared__ float Bs[8][64];
  int tid = threadIdx.x;
  int tx = tid & 15, ty = tid >> 4;
  int row0 = blockIdx.y * 64, col0 = blockIdx.x * 64;
  float acc[4][4] = {};
  for (int kt = 0; kt < K; kt += 8) {
#pragma unroll
    for (int i = 0; i < 2; i++) {
      int idx = tid + i * 256;
      int ka = idx & 7, ma = idx >> 3;
      As[ka][ma] = A[(size_t)(row0 + ma) * K + kt + ka];
      int nb = idx & 63, kb = idx >> 6;
      Bs[kb][nb] = B[(size_t)(kt + kb) * N + col0 + nb];
    }
    __syncthreads();
#pragma unroll
    for (int k = 0; k < 8; k++) {
      float a[4], b[4];
#pragma unroll
      for (int i = 0; i < 4; i++) a[i] = As[k][ty * 4 + i];
#pragma unroll
      for (int j = 0; j < 4; j++) b[j] = Bs[k][tx * 4 + j];
#pragma unroll
      for (int i = 0; i < 4; i++)
#pragma unroll
        for (int j = 0; j < 4; j++) acc[i][j] += a[i] * b[j];
    }
    __syncthreads();
  }
#pragma unroll
  for (int i = 0; i < 4; i++)
#pragma unroll
    for (int j = 0; j < 4; j++)
      C[(size_t)(row0 + ty * 4 + i) * N + col0 + tx * 4 + j] = acc[i][j];
}

// ---------------- attention scalars ----------------

// we_dot[h] = sum_c We[0,h*64+c] * ae[h,c]   (block = H*64 threads)
__global__ void k_wedot(const float* __restrict__ We, const float* __restrict__ ae,
                        float* __restrict__ wedot, int H) {
  int tid = threadIdx.x;
  int h = tid >> 6, c = tid & 63;
  float v = We[tid] * ae[tid];
  v = wredSum(v);
  if (c == 0) wedot[h] = v;
}

// a_s[n,h], a_d[n,h] : per-node per-head dots (block = H*64, one wave per head)
__global__ void k_node_attn(const float* __restrict__ hsrc, const float* __restrict__ as_,
                            const float* __restrict__ ad_, float* __restrict__ a_s,
                            float* __restrict__ a_d, int H) {
  int n = blockIdx.x;
  int tid = threadIdx.x;
  int hh = tid >> 6, c = tid & 63;
  float v = hsrc[(size_t)n * (H << 6) + tid];
  float vs = wredSum(v * as_[tid]);
  float vd = wredSum(v * ad_[tid]);
  if (c == 0) { a_s[n * H + hh] = vs; a_d[n * H + hh] = vd; }
}

// pre-softmax alpha for all E real edges + N self-loops
__global__ void k_edge_alpha(const int* __restrict__ ei, const float* __restrict__ ea,
                             const float* __restrict__ lea, const float* __restrict__ a_s,
                             const float* __restrict__ a_d, const float* __restrict__ wedot,
                             float* __restrict__ ealpha, int H) {
  int e = blockIdx.x * blockDim.x + threadIdx.x;
  if (e >= kE + kN) return;
  int s, d;
  float ev;
  if (e < kE) {
    s = ei[e];
    d = ei[kE + e];
    ev = ea[e];
    if (ev != ev) ev = 0.f;
  } else {
    s = d = e - kE;
    ev = lea[s];
  }
  for (int h = 0; h < H; h++) {
    float a = a_s[s * H + h] + a_d[d * H + h] + ev * wedot[h];
    ealpha[(size_t)e * H + h] = (a > 0.f) ? a : 0.2f * a;
  }
}

// ---------------- softmax-aggregate (one block per dst node) ----------------
// block = H*64 threads; wave w handles head w. Self-loop is implicit edge kE+d.
__global__ void k_agg(const float* __restrict__ hbuf, const float* __restrict__ ealpha,
                      const int* __restrict__ ei, const int* __restrict__ rowp,
                      const int* __restrict__ deg, const int* __restrict__ eidl,
                      const float* __restrict__ bias, const float* __restrict__ bng,
                      const float* __restrict__ bnb, const float* __restrict__ bnm,
                      const float* __restrict__ bnv, float* __restrict__ xout,
                      int H, int doBN) {
  int d = blockIdx.x;
  int tid = threadIdx.x;
  int h = tid >> 6, lane = tid & 63;
  int HC = H << 6;
  int start = rowp[d], dg = deg[d], total = dg + 1;

  float mx = -1e30f;
  for (int k = lane; k < total; k += 64) {
    int e = (k < dg) ? eidl[start + k] : (kE + d);
    mx = fmaxf(mx, ealpha[(size_t)e * H + h]);
  }
  mx = wredMax(mx);

  float sz = 0.f;
  for (int k = lane; k < total; k += 64) {
    int e = (k < dg) ? eidl[start + k] : (kE + d);
    sz += __expf(ealpha[(size_t)e * H + h] - mx);
  }
  sz = wredSum(sz);

  float acc = 0.f;
  for (int k = 0; k < total; k++) {
    int e, s;
    if (k < dg) { e = eidl[start + k]; s = ei[e]; }
    else        { e = kE + d;          s = d;     }
    float w = __expf(ealpha[(size_t)e * H + h] - mx);
    acc += w * hbuf[(size_t)s * HC + tid];
  }
  acc /= (sz + 1e-16f);
  acc += bias[tid];
  if (doBN) {
    float g = bng[tid], bb = bnb[tid];
    float m = bnm[tid], vv = bnv[tid];
    acc = (acc - m) * rsqrtf(vv + BN_EPS_) * g + bb;
    acc = fmaxf(acc, 0.f);  // ReLU
  }
  xout[(size_t)d * HC + tid] = acc;
}

// ---------------- mean pool + MLP head ----------------

__global__ void k_pool(const float* __restrict__ xin, const int* __restrict__ bat,
                       float* __restrict__ gsum, int* __restrict__ gcnt) {
  int i = blockIdx.x * blockDim.x + threadIdx.x;
  if (i >= kN * 64) return;
  int n = i >> 6, c = i & 63;
  int b = bat[n];
  atomicAdd(&gsum[b * 64 + c], xin[i]);
  if (c == 0) atomicAdd(&gcnt[b], 1);
}

__global__ void k_head(const float* __restrict__ gsum, const int* __restrict__ gcnt,
                       const float* __restrict__ cw1, const float* __restrict__ cb1,
                       const float* __restrict__ cw2, const float* __restrict__ cb2,
                       float* __restrict__ out) {
  __shared__ float gb[64], hb[64];
  int g = blockIdx.x, j = threadIdx.x;
  float cnt = fmaxf((float)gcnt[g], 1.f);
  gb[j] = gsum[g * 64 + j] / cnt;
  __syncthreads();
  float s = cb1[j];
#pragma unroll 8
  for (int i = 0; i < 64; i++) s += gb[i] * cw1[i * 64 + j];
  s = 0.5f * s * (1.f + erff(s * 0.70710678118654752f));  // exact GELU
  hb[j] = s;
  __syncthreads();
  if (j < 2) {
    float o = cb2[j];
    for (int i = 0; i < 64; i++) o += hb[i] * cw2[i * 2 + j];
    out[g * 2 + j] = o;
  }
}

// ---------------- launch ----------------

extern "C" void kernel_launch(void* const* d_in, const int* in_sizes, int n_in,
                              void* d_out, int out_size, void* d_ws, size_t ws_size,
                              hipStream_t stream) {
  (void)in_sizes; (void)n_in; (void)out_size; (void)ws_size;
  const float* x  = (const float*)d_in[0];
  const int* ei   = (const int*)d_in[1];
  const float* ea = (const float*)d_in[2];
  const int* bat  = (const int*)d_in[3];
  const float *W[3], *as_[3], *ad_[3], *We[3], *ae[3], *bi[3];
  for (int l = 0; l < 3; l++) {
    W[l]   = (const float*)d_in[4 + l * 6 + 0];
    as_[l] = (const float*)d_in[4 + l * 6 + 1];
    ad_[l] = (const float*)d_in[4 + l * 6 + 2];
    We[l]  = (const float*)d_in[4 + l * 6 + 3];
    ae[l]  = (const float*)d_in[4 + l * 6 + 4];
    bi[l]  = (const float*)d_in[4 + l * 6 + 5];
  }
  const float* bng = (const float*)d_in[22];
  const float* bnb = (const float*)d_in[23];
  const float* bnm = (const float*)d_in[24];
  const float* bnv = (const float*)d_in[25];
  const float* cw1 = (const float*)d_in[26];
  const float* cb1 = (const float*)d_in[27];
  const float* cw2 = (const float*)d_in[28];
  const float* cb2 = (const float*)d_in[29];

  char* p = (char*)d_ws;
  auto alloc = [&](size_t bytes) -> void* {
    void* r = (void*)p;
    p += (bytes + 255) & ~(size_t)255;
    return r;
  };
  // Region R0: x2 (fp32 [N,400], dies after L0 gemm) aliased with bufB
  // (fp32 [N,256], born at L1 agg) — lifetimes disjoint.
  void* R0      = alloc((size_t)kN * kIN2 * 4);
  float* x2     = (float*)R0;
  float* bufB   = (float*)R0;
  float* hbuf   = (float*)alloc((size_t)kN * 256 * 4);
  float* bufA   = (float*)alloc((size_t)kN * 256 * 4);
  float* ealpha = (float*)alloc((size_t)(kE + kN) * 4 * 4);
  float* a_s    = (float*)alloc((size_t)kN * 4 * 4);
  float* a_d    = (float*)alloc((size_t)kN * 4 * 4);
  int* rowp     = (int*)alloc((size_t)kN * 4);
  int* eidl     = (int*)alloc((size_t)kE * 4);
  float* lea    = (float*)alloc((size_t)kN * 4);
  float* wedot  = (float*)alloc(256);
  int* csum     = (int*)alloc(256);
  int* coff     = (int*)alloc(256);
  // zero-init region
  char* z0 = p;
  int* deg    = (int*)alloc((size_t)kN * 4);
  float* easum= (float*)alloc((size_t)kN * 4);
  int* cur    = (int*)alloc((size_t)kN * 4);
  float* gsum = (float*)alloc((size_t)kG * 64 * 4);
  int* gcnt   = (int*)alloc((size_t)kG * 4);
  int zwords = (int)((size_t)(p - z0) / 4);
  k_zero<<<(zwords + 255) / 256, 256, 0, stream>>>((unsigned int*)z0, zwords);

  // preprocessing + CSR
  k_prep_x<<<(kN * kIN + 255) / 256, 256, 0, stream>>>(x, x2);
  k_edge_deg<<<(kE + 255) / 256, 256, 0, stream>>>(ei, ea, deg, easum);
  k_scan_chunk<<<kN / 1024, 1024, 0, stream>>>(deg, rowp, csum);
  k_scan_sums<<<1, 64, 0, stream>>>(csum, coff, kN / 1024);
  k_scan_fix<<<(kN + 255) / 256, 256, 0, stream>>>(rowp, coff, deg, easum, lea);
  k_scatter<<<(kE + 255) / 256, 256, 0, stream>>>(ei, rowp, cur, eidl);

  int Kd[3] = {kIN2, 256, 256};
  int Nd[3] = {256, 256, 64};
  int Hh[3] = {4, 4, 1};
  int doBN[3] = {1, 1, 0};
  const float* lin[3] = {x2, bufA, bufB};
  float* lout[3] = {bufA, bufB, bufA};

  for (int l = 0; l < 3; l++) {
    dim3 gg(Nd[l] / 64, kN / 64);
    k_gemm<<<gg, 256, 0, stream>>>(lin[l], W[l], hbuf, kN, Nd[l], Kd[l]);
    k_wedot<<<1, Hh[l] * 64, 0, stream>>>(We[l], ae[l], wedot, Hh[l]);
    k_node_attn<<<kN, Hh[l] * 64, 0, stream>>>(hbuf, as_[l], ad_[l], a_s, a_d, Hh[l]);
    k_edge_alpha<<<(kE + kN + 255) / 256, 256, 0, stream>>>(ei, ea, lea, a_s, a_d,
                                                            wedot, ealpha, Hh[l]);
    k_agg<<<kN, Hh[l] * 64, 0, stream>>>(hbuf, ealpha, ei, rowp, deg, eidl, bi[l],
                                         bng, bnb, bnm, bnv, lout[l], Hh[l], doBN[l]);
  }

  k_pool<<<(kN * 64 + 255) / 256, 256, 0, stream>>>(bufA, bat, gsum, gcnt);
  k_head<<<kG, 64, 0, stream>>>(gsum, gcnt, cw1, cb1, cw2, cb2, (float*)d_out);
}

// Round 4
// 742.791 us; speedup vs baseline: 1.2388x; 1.2388x over previous
//
#include <hip/hip_runtime.h>
#include <hip/hip_bf16.h>

static const int kN  = 25600;   // nodes
static const int kE  = 409600;  // edges
static const int kG  = 128;     // graphs
static const int kIN = 200;     // raw feature dim
static const int kIN2 = 400;    // after nan-mask concat
#define BN_EPS_ 1e-5f

__device__ __forceinline__ float wredSum(float v) {
#pragma unroll
  for (int off = 1; off < 64; off <<= 1) v += __shfl_xor(v, off, 64);
  return v;
}
__device__ __forceinline__ float wredMax(float v) {
#pragma unroll
  for (int off = 1; off < 64; off <<= 1) v = fmaxf(v, __shfl_xor(v, off, 64));
  return v;
}

// zero n 32-bit words
__global__ void k_zero(unsigned int* __restrict__ p, int n) {
  int i = blockIdx.x * blockDim.x + threadIdx.x;
  if (i < n) p[i] = 0u;
}

// ---------------- preprocessing ----------------

// x[N,200] f32 -> x2[N,400] f32 = [nan_to_num(x), isnan(x)]
__global__ void k_prep_x(const float* __restrict__ x, float* __restrict__ x2) {
  int i = blockIdx.x * blockDim.x + threadIdx.x;
  if (i >= kN * kIN) return;
  int n = i / kIN, j = i - n * kIN;
  float v = x[i];
  bool bad = (v != v);
  x2[(size_t)n * kIN2 + j] = bad ? 0.f : v;
  x2[(size_t)n * kIN2 + kIN + j] = bad ? 1.f : 0.f;
}

// per-dst in-degree + sum of nan_to_num(edge_attr)
__global__ void k_edge_deg(const int* __restrict__ ei, const float* __restrict__ ea,
                           int* __restrict__ deg, float* __restrict__ easum) {
  int e = blockIdx.x * blockDim.x + threadIdx.x;
  if (e >= kE) return;
  int d = ei[kE + e];
  atomicAdd(&deg[d], 1);
  float v = ea[e];
  if (v != v) v = 0.f;
  atomicAdd(&easum[d], v);
}

// exclusive scan of deg -> rowp  (25 chunks of 1024; kN == 25*1024)
__global__ void k_scan_chunk(const int* __restrict__ deg, int* __restrict__ rowp,
                             int* __restrict__ csum) {
  __shared__ int s[1024];
  int tid = threadIdx.x;
  int i = blockIdx.x * 1024 + tid;
  int v = deg[i];
  s[tid] = v;
  __syncthreads();
  for (int off = 1; off < 1024; off <<= 1) {
    int t = (tid >= off) ? s[tid - off] : 0;
    __syncthreads();
    s[tid] += t;
    __syncthreads();
  }
  rowp[i] = s[tid] - v;  // exclusive within chunk
  if (tid == 1023) csum[blockIdx.x] = s[tid];
}

__global__ void k_scan_sums(const int* __restrict__ csum, int* __restrict__ coff, int nchunk) {
  if (threadIdx.x == 0 && blockIdx.x == 0) {
    int acc = 0;
    for (int i = 0; i < nchunk; i++) { coff[i] = acc; acc += csum[i]; }
  }
}

__global__ void k_scan_fix(int* __restrict__ rowp, const int* __restrict__ coff,
                           const int* __restrict__ deg, const float* __restrict__ easum,
                           float* __restrict__ lea) {
  int i = blockIdx.x * blockDim.x + threadIdx.x;
  if (i >= kN) return;
  rowp[i] += coff[i >> 10];
  float c = (float)deg[i];
  lea[i] = easum[i] / fmaxf(c, 1.f);  // mean incoming edge attr (self-loop fill)
}

// CSR row d occupies slots [rowp[d]+d, rowp[d]+d+deg[d]+1); last slot = self-loop.
__global__ void k_scatter(const int* __restrict__ ei, const int* __restrict__ rowp,
                          int* __restrict__ cur, int* __restrict__ esrc,
                          int* __restrict__ slotOf) {
  int e = blockIdx.x * blockDim.x + threadIdx.x;
  if (e >= kE) return;
  int d = ei[kE + e];
  int pos = atomicAdd(&cur[d], 1);
  int slot = rowp[d] + d + pos;
  esrc[slot] = ei[e];
  slotOf[e] = slot;
}

// self-loop src entries (once, layer-independent)
__global__ void k_selfsrc(const int* __restrict__ rowp, const int* __restrict__ deg,
                          int* __restrict__ esrc) {
  int d = blockIdx.x * blockDim.x + threadIdx.x;
  if (d >= kN) return;
  esrc[rowp[d] + d + deg[d]] = d;
}

// ---------------- GEMM: C[M,N] = A[M,K] @ B[K,N], fp32 ----------------
// 64x64 tile, 256 threads, 4x4 micro-tile. M%64==0, N%64==0, K%8==0 hold here.
__global__ void k_gemm(const float* __restrict__ A, const float* __restrict__ B,
                       float* __restrict__ C, int M, int N, int K) {
  __shared__ float As[8][64];
  __shared__ float Bs[8][64];
  int tid = threadIdx.x;
  int tx = tid & 15, ty = tid >> 4;
  int row0 = blockIdx.y * 64, col0 = blockIdx.x * 64;
  float acc[4][4] = {};
  for (int kt = 0; kt < K; kt += 8) {
#pragma unroll
    for (int i = 0; i < 2; i++) {
      int idx = tid + i * 256;
      int ka = idx & 7, ma = idx >> 3;
      As[ka][ma] = A[(size_t)(row0 + ma) * K + kt + ka];
      int nb = idx & 63, kb = idx >> 6;
      Bs[kb][nb] = B[(size_t)(kt + kb) * N + col0 + nb];
    }
    __syncthreads();
#pragma unroll
    for (int k = 0; k < 8; k++) {
      float a[4], b[4];
#pragma unroll
      for (int i = 0; i < 4; i++) a[i] = As[k][ty * 4 + i];
#pragma unroll
      for (int j = 0; j < 4; j++) b[j] = Bs[k][tx * 4 + j];
#pragma unroll
      for (int i = 0; i < 4; i++)
#pragma unroll
        for (int j = 0; j < 4; j++) acc[i][j] += a[i] * b[j];
    }
    __syncthreads();
  }
#pragma unroll
  for (int i = 0; i < 4; i++)
#pragma unroll
    for (int j = 0; j < 4; j++)
      C[(size_t)(row0 + ty * 4 + i) * N + col0 + tx * 4 + j] = acc[i][j];
}

// ---------------- attention scalars ----------------

// we_dot[h] = sum_c We[0,h*64+c] * ae[h,c]   (block = H*64 threads)
__global__ void k_wedot(const float* __restrict__ We, const float* __restrict__ ae,
                        float* __restrict__ wedot, int H) {
  int tid = threadIdx.x;
  int h = tid >> 6, c = tid & 63;
  float v = We[tid] * ae[tid];
  v = wredSum(v);
  if (c == 0) wedot[h] = v;
}

// a_s[n,h], a_d[n,h] : per-node per-head dots (block = H*64, one wave per head)
__global__ void k_node_attn(const float* __restrict__ hsrc, const float* __restrict__ as_,
                            const float* __restrict__ ad_, float* __restrict__ a_s,
                            float* __restrict__ a_d, int H) {
  int n = blockIdx.x;
  int tid = threadIdx.x;
  int hh = tid >> 6, c = tid & 63;
  float v = hsrc[(size_t)n * (H << 6) + tid];
  float vs = wredSum(v * as_[tid]);
  float vd = wredSum(v * ad_[tid]);
  if (c == 0) { a_s[n * H + hh] = vs; a_d[n * H + hh] = vd; }
}

// pre-softmax leaky-relu'd logits, scattered into CSR order: walpha[slot*H+h]
__global__ void k_alpha(const int* __restrict__ ei, const float* __restrict__ ea,
                        const float* __restrict__ lea, const int* __restrict__ rowp,
                        const int* __restrict__ deg, const int* __restrict__ slotOf,
                        const float* __restrict__ a_s, const float* __restrict__ a_d,
                        const float* __restrict__ wedot, float* __restrict__ walpha,
                        int H) {
  int e = blockIdx.x * blockDim.x + threadIdx.x;
  if (e >= kE + kN) return;
  int s, d, slot;
  float ev;
  if (e < kE) {
    s = ei[e];
    d = ei[kE + e];
    ev = ea[e];
    if (ev != ev) ev = 0.f;
    slot = slotOf[e];
  } else {
    int n = e - kE;
    s = d = n;
    ev = lea[n];
    slot = rowp[n] + n + deg[n];
  }
  for (int h = 0; h < H; h++) {
    float a = a_s[s * H + h] + a_d[d * H + h] + ev * wedot[h];
    walpha[(size_t)slot * H + h] = (a > 0.f) ? a : 0.2f * a;
  }
}

// ---------------- softmax-aggregate (one block per dst node) ----------------
// block = H*64; wave h owns head h. CSR-linear logits; LDS-staged gather w/ 4x MLP.
#define AGG_CH 256
__global__ void k_agg(const float* __restrict__ hbuf, const float* __restrict__ walpha,
                      const int* __restrict__ rowp, const int* __restrict__ deg,
                      const int* __restrict__ esrc,
                      const float* __restrict__ bias, const float* __restrict__ bng,
                      const float* __restrict__ bnb, const float* __restrict__ bnm,
                      const float* __restrict__ bnv, float* __restrict__ xout,
                      int H, int doBN) {
  __shared__ int   lsrc[AGG_CH];
  __shared__ float lw[4][AGG_CH];
  int d = blockIdx.x;
  int tid = threadIdx.x;
  int h = tid >> 6, lane = tid & 63;
  int HC = H << 6;
  int start = rowp[d] + d;
  int total = deg[d] + 1;

  // per-head max & sum over linear walpha (wave-local, no block sync needed)
  float mx = -1e30f;
  for (int k = lane; k < total; k += 64)
    mx = fmaxf(mx, walpha[(size_t)(start + k) * H + h]);
  mx = wredMax(mx);
  float sz = 0.f;
  for (int k = lane; k < total; k += 64)
    sz += __expf(walpha[(size_t)(start + k) * H + h] - mx);
  sz = wredSum(sz);
  float winv = 1.f / (sz + 1e-16f);

  float acc = 0.f;
  for (int b = 0; b < total; b += AGG_CH) {
    int m = min(AGG_CH, total - b);
    __syncthreads();
    for (int j = tid; j < m; j += blockDim.x) lsrc[j] = esrc[start + b + j];
    for (int k = lane; k < m; k += 64)
      lw[h][k] = __expf(walpha[(size_t)(start + b + k) * H + h] - mx) * winv;
    __syncthreads();
    int k = 0;
    for (; k + 4 <= m; k += 4) {
      int s0 = lsrc[k], s1 = lsrc[k + 1], s2 = lsrc[k + 2], s3 = lsrc[k + 3];
      float v0 = hbuf[(size_t)s0 * HC + tid];
      float v1 = hbuf[(size_t)s1 * HC + tid];
      float v2 = hbuf[(size_t)s2 * HC + tid];
      float v3 = hbuf[(size_t)s3 * HC + tid];
      acc += lw[h][k] * v0 + lw[h][k + 1] * v1 + lw[h][k + 2] * v2 + lw[h][k + 3] * v3;
    }
    for (; k < m; k++) acc += lw[h][k] * hbuf[(size_t)lsrc[k] * HC + tid];
  }

  acc += bias[tid];
  if (doBN) {
    float g = bng[tid], bb = bnb[tid];
    float m2 = bnm[tid], vv = bnv[tid];
    acc = (acc - m2) * rsqrtf(vv + BN_EPS_) * g + bb;
    acc = fmaxf(acc, 0.f);  // ReLU
  }
  xout[(size_t)d * HC + tid] = acc;
}

// ---------------- mean pool + MLP head ----------------

__global__ void k_pool(const float* __restrict__ xin, const int* __restrict__ bat,
                       float* __restrict__ gsum, int* __restrict__ gcnt) {
  int i = blockIdx.x * blockDim.x + threadIdx.x;
  if (i >= kN * 64) return;
  int n = i >> 6, c = i & 63;
  int b = bat[n];
  atomicAdd(&gsum[b * 64 + c], xin[i]);
  if (c == 0) atomicAdd(&gcnt[b], 1);
}

__global__ void k_head(const float* __restrict__ gsum, const int* __restrict__ gcnt,
                       const float* __restrict__ cw1, const float* __restrict__ cb1,
                       const float* __restrict__ cw2, const float* __restrict__ cb2,
                       float* __restrict__ out) {
  __shared__ float gb[64], hb[64];
  int g = blockIdx.x, j = threadIdx.x;
  float cnt = fmaxf((float)gcnt[g], 1.f);
  gb[j] = gsum[g * 64 + j] / cnt;
  __syncthreads();
  float s = cb1[j];
#pragma unroll 8
  for (int i = 0; i < 64; i++) s += gb[i] * cw1[i * 64 + j];
  s = 0.5f * s * (1.f + erff(s * 0.70710678118654752f));  // exact GELU
  hb[j] = s;
  __syncthreads();
  if (j < 2) {
    float o = cb2[j];
    for (int i = 0; i < 64; i++) o += hb[i] * cw2[i * 2 + j];
    out[g * 2 + j] = o;
  }
}

// ---------------- launch ----------------

extern "C" void kernel_launch(void* const* d_in, const int* in_sizes, int n_in,
                              void* d_out, int out_size, void* d_ws, size_t ws_size,
                              hipStream_t stream) {
  (void)in_sizes; (void)n_in; (void)out_size; (void)ws_size;
  const float* x  = (const float*)d_in[0];
  const int* ei   = (const int*)d_in[1];
  const float* ea = (const float*)d_in[2];
  const int* bat  = (const int*)d_in[3];
  const float *W[3], *as_[3], *ad_[3], *We[3], *ae[3], *bi[3];
  for (int l = 0; l < 3; l++) {
    W[l]   = (const float*)d_in[4 + l * 6 + 0];
    as_[l] = (const float*)d_in[4 + l * 6 + 1];
    ad_[l] = (const float*)d_in[4 + l * 6 + 2];
    We[l]  = (const float*)d_in[4 + l * 6 + 3];
    ae[l]  = (const float*)d_in[4 + l * 6 + 4];
    bi[l]  = (const float*)d_in[4 + l * 6 + 5];
  }
  const float* bng = (const float*)d_in[22];
  const float* bnb = (const float*)d_in[23];
  const float* bnm = (const float*)d_in[24];
  const float* bnv = (const float*)d_in[25];
  const float* cw1 = (const float*)d_in[26];
  const float* cb1 = (const float*)d_in[27];
  const float* cw2 = (const float*)d_in[28];
  const float* cb2 = (const float*)d_in[29];

  char* p = (char*)d_ws;
  auto alloc = [&](size_t bytes) -> void* {
    void* r = (void*)p;
    p += (bytes + 255) & ~(size_t)255;
    return r;
  };
  // Region R0: x2 (fp32 [N,400], dies after L0 gemm) aliased with bufB
  // (fp32 [N,256], born at L1 agg) — lifetimes disjoint.
  void* R0      = alloc((size_t)kN * kIN2 * 4);
  float* x2     = (float*)R0;
  float* bufB   = (float*)R0;
  float* hbuf   = (float*)alloc((size_t)kN * 256 * 4);
  float* bufA   = (float*)alloc((size_t)kN * 256 * 4);
  float* walpha = (float*)alloc((size_t)(kE + kN) * 4 * 4);
  float* a_s    = (float*)alloc((size_t)kN * 4 * 4);
  float* a_d    = (float*)alloc((size_t)kN * 4 * 4);
  int* rowp     = (int*)alloc((size_t)kN * 4);
  int* esrc     = (int*)alloc((size_t)(kE + kN) * 4);
  int* slotOf   = (int*)alloc((size_t)kE * 4);
  float* lea    = (float*)alloc((size_t)kN * 4);
  float* wedot  = (float*)alloc(256);
  int* csum     = (int*)alloc(256);
  int* coff     = (int*)alloc(256);
  // zero-init region
  char* z0 = p;
  int* deg    = (int*)alloc((size_t)kN * 4);
  float* easum= (float*)alloc((size_t)kN * 4);
  int* cur    = (int*)alloc((size_t)kN * 4);
  float* gsum = (float*)alloc((size_t)kG * 64 * 4);
  int* gcnt   = (int*)alloc((size_t)kG * 4);
  int zwords = (int)((size_t)(p - z0) / 4);
  k_zero<<<(zwords + 255) / 256, 256, 0, stream>>>((unsigned int*)z0, zwords);

  // preprocessing + CSR
  k_prep_x<<<(kN * kIN + 255) / 256, 256, 0, stream>>>(x, x2);
  k_edge_deg<<<(kE + 255) / 256, 256, 0, stream>>>(ei, ea, deg, easum);
  k_scan_chunk<<<kN / 1024, 1024, 0, stream>>>(deg, rowp, csum);
  k_scan_sums<<<1, 64, 0, stream>>>(csum, coff, kN / 1024);
  k_scan_fix<<<(kN + 255) / 256, 256, 0, stream>>>(rowp, coff, deg, easum, lea);
  k_scatter<<<(kE + 255) / 256, 256, 0, stream>>>(ei, rowp, cur, esrc, slotOf);
  k_selfsrc<<<(kN + 255) / 256, 256, 0, stream>>>(rowp, deg, esrc);

  int Kd[3] = {kIN2, 256, 256};
  int Nd[3] = {256, 256, 64};
  int Hh[3] = {4, 4, 1};
  int doBN[3] = {1, 1, 0};
  const float* lin[3] = {x2, bufA, bufB};
  float* lout[3] = {bufA, bufB, bufA};

  for (int l = 0; l < 3; l++) {
    dim3 gg(Nd[l] / 64, kN / 64);
    k_gemm<<<gg, 256, 0, stream>>>(lin[l], W[l], hbuf, kN, Nd[l], Kd[l]);
    k_wedot<<<1, Hh[l] * 64, 0, stream>>>(We[l], ae[l], wedot, Hh[l]);
    k_node_attn<<<kN, Hh[l] * 64, 0, stream>>>(hbuf, as_[l], ad_[l], a_s, a_d, Hh[l]);
    k_alpha<<<(kE + kN + 255) / 256, 256, 0, stream>>>(ei, ea, lea, rowp, deg, slotOf,
                                                       a_s, a_d, wedot, walpha, Hh[l]);
    k_agg<<<kN, Hh[l] * 64, 0, stream>>>(hbuf, walpha, rowp, deg, esrc, bi[l],
                                         bng, bnb, bnm, bnv, lout[l], Hh[l], doBN[l]);
  }

  k_pool<<<(kN * 64 + 255) / 256, 256, 0, stream>>>(bufA, bat, gsum, gcnt);
  k_head<<<kG, 64, 0, stream>>>(gsum, gcnt, cw1, cb1, cw2, cb2, (float*)d_out);
}

// Round 5
// 656.090 us; speedup vs baseline: 1.4025x; 1.1321x over previous
//
#include <hip/hip_runtime.h>
#include <hip/hip_bf16.h>

static const int kN  = 25600;   // nodes
static const int kE  = 409600;  // edges
static const int kG  = 128;     // graphs
static const int kNPG = 200;    // nodes per graph (batch = repeat(arange(G), N/G))
static const int kIN = 200;     // raw feature dim
static const int kIN2 = 400;    // after nan-mask concat
#define BN_EPS_ 1e-5f

__device__ __forceinline__ float wredSum(float v) {
#pragma unroll
  for (int off = 1; off < 64; off <<= 1) v += __shfl_xor(v, off, 64);
  return v;
}
__device__ __forceinline__ float wredMax(float v) {
#pragma unroll
  for (int off = 1; off < 64; off <<= 1) v = fmaxf(v, __shfl_xor(v, off, 64));
  return v;
}

// zero n 32-bit words
__global__ void k_zero(unsigned int* __restrict__ p, int n) {
  int i = blockIdx.x * blockDim.x + threadIdx.x;
  if (i < n) p[i] = 0u;
}

// ---------------- preprocessing ----------------

// x[N,200] f32 -> x2[N,400] f32 = [nan_to_num(x), isnan(x)]
__global__ void k_prep_x(const float* __restrict__ x, float* __restrict__ x2) {
  int i = blockIdx.x * blockDim.x + threadIdx.x;
  if (i >= kN * kIN) return;
  int n = i / kIN, j = i - n * kIN;
  float v = x[i];
  bool bad = (v != v);
  x2[(size_t)n * kIN2 + j] = bad ? 0.f : v;
  x2[(size_t)n * kIN2 + kIN + j] = bad ? 1.f : 0.f;
}

// per-dst in-degree + sum of nan_to_num(edge_attr)
__global__ void k_edge_deg(const int* __restrict__ ei, const float* __restrict__ ea,
                           int* __restrict__ deg, float* __restrict__ easum) {
  int e = blockIdx.x * blockDim.x + threadIdx.x;
  if (e >= kE) return;
  int d = ei[kE + e];
  atomicAdd(&deg[d], 1);
  float v = ea[e];
  if (v != v) v = 0.f;
  atomicAdd(&easum[d], v);
}

// exclusive scan of deg -> rowp  (25 chunks of 1024; kN == 25*1024)
__global__ void k_scan_chunk(const int* __restrict__ deg, int* __restrict__ rowp,
                             int* __restrict__ csum) {
  __shared__ int s[1024];
  int tid = threadIdx.x;
  int i = blockIdx.x * 1024 + tid;
  int v = deg[i];
  s[tid] = v;
  __syncthreads();
  for (int off = 1; off < 1024; off <<= 1) {
    int t = (tid >= off) ? s[tid - off] : 0;
    __syncthreads();
    s[tid] += t;
    __syncthreads();
  }
  rowp[i] = s[tid] - v;  // exclusive within chunk
  if (tid == 1023) csum[blockIdx.x] = s[tid];
}

__global__ void k_scan_sums(const int* __restrict__ csum, int* __restrict__ coff, int nchunk) {
  if (threadIdx.x == 0 && blockIdx.x == 0) {
    int acc = 0;
    for (int i = 0; i < nchunk; i++) { coff[i] = acc; acc += csum[i]; }
  }
}

__global__ void k_scan_fix(int* __restrict__ rowp, const int* __restrict__ coff,
                           const int* __restrict__ deg, const float* __restrict__ easum,
                           float* __restrict__ lea) {
  int i = blockIdx.x * blockDim.x + threadIdx.x;
  if (i >= kN) return;
  rowp[i] += coff[i >> 10];
  float c = (float)deg[i];
  lea[i] = easum[i] / fmaxf(c, 1.f);  // mean incoming edge attr (self-loop fill)
}

// CSR row d occupies slots [rowp[d]+d, rowp[d]+d+deg[d]+1); last slot = self-loop.
__global__ void k_scatter(const int* __restrict__ ei, const int* __restrict__ rowp,
                          int* __restrict__ cur, int* __restrict__ esrc,
                          int* __restrict__ slotOf) {
  int e = blockIdx.x * blockDim.x + threadIdx.x;
  if (e >= kE) return;
  int d = ei[kE + e];
  int pos = atomicAdd(&cur[d], 1);
  int slot = rowp[d] + d + pos;
  esrc[slot] = ei[e];
  slotOf[e] = slot;
}

// self-loop src entries (once, layer-independent)
__global__ void k_selfsrc(const int* __restrict__ rowp, const int* __restrict__ deg,
                          int* __restrict__ esrc) {
  int d = blockIdx.x * blockDim.x + threadIdx.x;
  if (d >= kN) return;
  esrc[rowp[d] + d + deg[d]] = d;
}

// ---------------- GEMM: C[M,N] = A[M,K] @ B[K,N], fp32 ----------------
// 64x64 tile, 256 threads, 4x4 micro-tile. M%64==0, N%64==0, K%8==0 hold here.
__global__ void k_gemm(const float* __restrict__ A, const float* __restrict__ B,
                       float* __restrict__ C, int M, int N, int K) {
  __shared__ float As[8][64];
  __shared__ float Bs[8][64];
  int tid = threadIdx.x;
  int tx = tid & 15, ty = tid >> 4;
  int row0 = blockIdx.y * 64, col0 = blockIdx.x * 64;
  float acc[4][4] = {};
  for (int kt = 0; kt < K; kt += 8) {
#pragma unroll
    for (int i = 0; i < 2; i++) {
      int idx = tid + i * 256;
      int ka = idx & 7, ma = idx >> 3;
      As[ka][ma] = A[(size_t)(row0 + ma) * K + kt + ka];
      int nb = idx & 63, kb = idx >> 6;
      Bs[kb][nb] = B[(size_t)(kt + kb) * N + col0 + nb];
    }
    __syncthreads();
#pragma unroll
    for (int k = 0; k < 8; k++) {
      float a[4], b[4];
#pragma unroll
      for (int i = 0; i < 4; i++) a[i] = As[k][ty * 4 + i];
#pragma unroll
      for (int j = 0; j < 4; j++) b[j] = Bs[k][tx * 4 + j];
#pragma unroll
      for (int i = 0; i < 4; i++)
#pragma unroll
        for (int j = 0; j < 4; j++) acc[i][j] += a[i] * b[j];
    }
    __syncthreads();
  }
#pragma unroll
  for (int i = 0; i < 4; i++)
#pragma unroll
    for (int j = 0; j < 4; j++)
      C[(size_t)(row0 + ty * 4 + i) * N + col0 + tx * 4 + j] = acc[i][j];
}

// ---------------- attention scalars ----------------

// we_dot[h] = sum_c We[0,h*64+c] * ae[h,c]   (block = H*64 threads)
__global__ void k_wedot(const float* __restrict__ We, const float* __restrict__ ae,
                        float* __restrict__ wedot, int H) {
  int tid = threadIdx.x;
  int h = tid >> 6, c = tid & 63;
  float v = We[tid] * ae[tid];
  v = wredSum(v);
  if (c == 0) wedot[h] = v;
}

// a_s[n,h], a_d[n,h] : per-node per-head dots (block = H*64, one wave per head)
__global__ void k_node_attn(const float* __restrict__ hsrc, const float* __restrict__ as_,
                            const float* __restrict__ ad_, float* __restrict__ a_s,
                            float* __restrict__ a_d, int H) {
  int n = blockIdx.x;
  int tid = threadIdx.x;
  int hh = tid >> 6, c = tid & 63;
  float v = hsrc[(size_t)n * (H << 6) + tid];
  float vs = wredSum(v * as_[tid]);
  float vd = wredSum(v * ad_[tid]);
  if (c == 0) { a_s[n * H + hh] = vs; a_d[n * H + hh] = vd; }
}

// pre-softmax leaky-relu'd logits, scattered into CSR order: walpha[slot*H+h]
__global__ void k_alpha(const int* __restrict__ ei, const float* __restrict__ ea,
                        const float* __restrict__ lea, const int* __restrict__ rowp,
                        const int* __restrict__ deg, const int* __restrict__ slotOf,
                        const float* __restrict__ a_s, const float* __restrict__ a_d,
                        const float* __restrict__ wedot, float* __restrict__ walpha,
                        int H) {
  int e = blockIdx.x * blockDim.x + threadIdx.x;
  if (e >= kE + kN) return;
  int s, d, slot;
  float ev;
  if (e < kE) {
    s = ei[e];
    d = ei[kE + e];
    ev = ea[e];
    if (ev != ev) ev = 0.f;
    slot = slotOf[e];
  } else {
    int n = e - kE;
    s = d = n;
    ev = lea[n];
    slot = rowp[n] + n + deg[n];
  }
  for (int h = 0; h < H; h++) {
    float a = a_s[s * H + h] + a_d[d * H + h] + ev * wedot[h];
    walpha[(size_t)slot * H + h] = (a > 0.f) ? a : 0.2f * a;
  }
}

// ---------------- softmax-aggregate (one block per dst node) ----------------
// block = H*64; wave h owns head h. CSR-linear logits; LDS-staged gather w/ 4x MLP.
#define AGG_CH 256
__global__ void k_agg(const float* __restrict__ hbuf, const float* __restrict__ walpha,
                      const int* __restrict__ rowp, const int* __restrict__ deg,
                      const int* __restrict__ esrc,
                      const float* __restrict__ bias, const float* __restrict__ bng,
                      const float* __restrict__ bnb, const float* __restrict__ bnm,
                      const float* __restrict__ bnv, float* __restrict__ xout,
                      int H, int doBN) {
  __shared__ int   lsrc[AGG_CH];
  __shared__ float lw[4][AGG_CH];
  int d = blockIdx.x;
  int tid = threadIdx.x;
  int h = tid >> 6, lane = tid & 63;
  int HC = H << 6;
  int start = rowp[d] + d;
  int total = deg[d] + 1;

  // per-head max & sum over linear walpha (wave-local, no block sync needed)
  float mx = -1e30f;
  for (int k = lane; k < total; k += 64)
    mx = fmaxf(mx, walpha[(size_t)(start + k) * H + h]);
  mx = wredMax(mx);
  float sz = 0.f;
  for (int k = lane; k < total; k += 64)
    sz += __expf(walpha[(size_t)(start + k) * H + h] - mx);
  sz = wredSum(sz);
  float winv = 1.f / (sz + 1e-16f);

  float acc = 0.f;
  for (int b = 0; b < total; b += AGG_CH) {
    int m = min(AGG_CH, total - b);
    __syncthreads();
    for (int j = tid; j < m; j += blockDim.x) lsrc[j] = esrc[start + b + j];
    for (int k = lane; k < m; k += 64)
      lw[h][k] = __expf(walpha[(size_t)(start + b + k) * H + h] - mx) * winv;
    __syncthreads();
    int k = 0;
    for (; k + 4 <= m; k += 4) {
      int s0 = lsrc[k], s1 = lsrc[k + 1], s2 = lsrc[k + 2], s3 = lsrc[k + 3];
      float v0 = hbuf[(size_t)s0 * HC + tid];
      float v1 = hbuf[(size_t)s1 * HC + tid];
      float v2 = hbuf[(size_t)s2 * HC + tid];
      float v3 = hbuf[(size_t)s3 * HC + tid];
      acc += lw[h][k] * v0 + lw[h][k + 1] * v1 + lw[h][k + 2] * v2 + lw[h][k + 3] * v3;
    }
    for (; k < m; k++) acc += lw[h][k] * hbuf[(size_t)lsrc[k] * HC + tid];
  }

  acc += bias[tid];
  if (doBN) {
    float g = bng[tid], bb = bnb[tid];
    float m2 = bnm[tid], vv = bnv[tid];
    acc = (acc - m2) * rsqrtf(vv + BN_EPS_) * g + bb;
    acc = fmaxf(acc, 0.f);  // ReLU
  }
  xout[(size_t)d * HC + tid] = acc;
}

// ---------------- fused mean-pool + MLP head ----------------
// batch = repeat(arange(G), 200): graph g owns nodes [g*200, (g+1)*200).
// One block (256 thr = 4 waves) per graph: dense strided reduction, no atomics.
__global__ void k_poolhead(const float* __restrict__ xin,
                           const float* __restrict__ cw1, const float* __restrict__ cb1,
                           const float* __restrict__ cw2, const float* __restrict__ cb2,
                           float* __restrict__ out) {
  __shared__ float part[4][64];
  __shared__ float gb[64], hb[64];
  int g = blockIdx.x, tid = threadIdx.x;
  int c = tid & 63, w = tid >> 6;
  float acc = 0.f;
  size_t base = (size_t)g * kNPG * 64;
  for (int n = w; n < kNPG; n += 4) acc += xin[base + (size_t)n * 64 + c];
  part[w][c] = acc;
  __syncthreads();
  if (tid < 64) {
    float s = (part[0][c] + part[1][c]) + (part[2][c] + part[3][c]);
    gb[c] = s * (1.f / kNPG);
  }
  __syncthreads();
  if (tid < 64) {
    float s = cb1[c];
#pragma unroll 8
    for (int i = 0; i < 64; i++) s += gb[i] * cw1[i * 64 + c];
    s = 0.5f * s * (1.f + erff(s * 0.70710678118654752f));  // exact GELU
    hb[c] = s;
  }
  __syncthreads();
  if (tid < 2) {
    float o = cb2[tid];
    for (int i = 0; i < 64; i++) o += hb[i] * cw2[i * 2 + tid];
    out[g * 2 + tid] = o;
  }
}

// ---------------- launch ----------------

extern "C" void kernel_launch(void* const* d_in, const int* in_sizes, int n_in,
                              void* d_out, int out_size, void* d_ws, size_t ws_size,
                              hipStream_t stream) {
  (void)in_sizes; (void)n_in; (void)out_size; (void)ws_size;
  const float* x  = (const float*)d_in[0];
  const int* ei   = (const int*)d_in[1];
  const float* ea = (const float*)d_in[2];
  const float *W[3], *as_[3], *ad_[3], *We[3], *ae[3], *bi[3];
  for (int l = 0; l < 3; l++) {
    W[l]   = (const float*)d_in[4 + l * 6 + 0];
    as_[l] = (const float*)d_in[4 + l * 6 + 1];
    ad_[l] = (const float*)d_in[4 + l * 6 + 2];
    We[l]  = (const float*)d_in[4 + l * 6 + 3];
    ae[l]  = (const float*)d_in[4 + l * 6 + 4];
    bi[l]  = (const float*)d_in[4 + l * 6 + 5];
  }
  const float* bng = (const float*)d_in[22];
  const float* bnb = (const float*)d_in[23];
  const float* bnm = (const float*)d_in[24];
  const float* bnv = (const float*)d_in[25];
  const float* cw1 = (const float*)d_in[26];
  const float* cb1 = (const float*)d_in[27];
  const float* cw2 = (const float*)d_in[28];
  const float* cb2 = (const float*)d_in[29];

  char* p = (char*)d_ws;
  auto alloc = [&](size_t bytes) -> void* {
    void* r = (void*)p;
    p += (bytes + 255) & ~(size_t)255;
    return r;
  };
  // Region R0: x2 (fp32 [N,400], dies after L0 gemm) aliased with bufB
  // (fp32 [N,256], born at L1 agg) — lifetimes disjoint.
  void* R0      = alloc((size_t)kN * kIN2 * 4);
  float* x2     = (float*)R0;
  float* bufB   = (float*)R0;
  float* hbuf   = (float*)alloc((size_t)kN * 256 * 4);
  float* bufA   = (float*)alloc((size_t)kN * 256 * 4);
  float* walpha = (float*)alloc((size_t)(kE + kN) * 4 * 4);
  float* a_s    = (float*)alloc((size_t)kN * 4 * 4);
  float* a_d    = (float*)alloc((size_t)kN * 4 * 4);
  int* rowp     = (int*)alloc((size_t)kN * 4);
  int* esrc     = (int*)alloc((size_t)(kE + kN) * 4);
  int* slotOf   = (int*)alloc((size_t)kE * 4);
  float* lea    = (float*)alloc((size_t)kN * 4);
  float* wedot  = (float*)alloc(256);
  int* csum     = (int*)alloc(256);
  int* coff     = (int*)alloc(256);
  // zero-init region
  char* z0 = p;
  int* deg    = (int*)alloc((size_t)kN * 4);
  float* easum= (float*)alloc((size_t)kN * 4);
  int* cur    = (int*)alloc((size_t)kN * 4);
  int zwords = (int)((size_t)(p - z0) / 4);
  k_zero<<<(zwords + 255) / 256, 256, 0, stream>>>((unsigned int*)z0, zwords);

  // preprocessing + CSR
  k_prep_x<<<(kN * kIN + 255) / 256, 256, 0, stream>>>(x, x2);
  k_edge_deg<<<(kE + 255) / 256, 256, 0, stream>>>(ei, ea, deg, easum);
  k_scan_chunk<<<kN / 1024, 1024, 0, stream>>>(deg, rowp, csum);
  k_scan_sums<<<1, 64, 0, stream>>>(csum, coff, kN / 1024);
  k_scan_fix<<<(kN + 255) / 256, 256, 0, stream>>>(rowp, coff, deg, easum, lea);
  k_scatter<<<(kE + 255) / 256, 256, 0, stream>>>(ei, rowp, cur, esrc, slotOf);
  k_selfsrc<<<(kN + 255) / 256, 256, 0, stream>>>(rowp, deg, esrc);

  int Kd[3] = {kIN2, 256, 256};
  int Nd[3] = {256, 256, 64};
  int Hh[3] = {4, 4, 1};
  int doBN[3] = {1, 1, 0};
  const float* lin[3] = {x2, bufA, bufB};
  float* lout[3] = {bufA, bufB, bufA};

  for (int l = 0; l < 3; l++) {
    dim3 gg(Nd[l] / 64, kN / 64);
    k_gemm<<<gg, 256, 0, stream>>>(lin[l], W[l], hbuf, kN, Nd[l], Kd[l]);
    k_wedot<<<1, Hh[l] * 64, 0, stream>>>(We[l], ae[l], wedot, Hh[l]);
    k_node_attn<<<kN, Hh[l] * 64, 0, stream>>>(hbuf, as_[l], ad_[l], a_s, a_d, Hh[l]);
    k_alpha<<<(kE + kN + 255) / 256, 256, 0, stream>>>(ei, ea, lea, rowp, deg, slotOf,
                                                       a_s, a_d, wedot, walpha, Hh[l]);
    k_agg<<<kN, Hh[l] * 64, 0, stream>>>(hbuf, walpha, rowp, deg, esrc, bi[l],
                                         bng, bnb, bnm, bnv, lout[l], Hh[l], doBN[l]);
  }

  k_poolhead<<<kG, 256, 0, stream>>>(bufA, cw1, cb1, cw2, cb2, (float*)d_out);
}